// Round 12
// baseline (59.264 us; speedup 1.0000x reference)
//
#include <hip/hip_runtime.h>
#include <hip/hip_bf16.h>
#include <math.h>

#define N_TOK 16384
#define D_DIM 2048
#define E_EXP 64
#define KQ    256               /* K per wave (eighth split) */
#define NKS   16                /* ksteps of K=16 per wave */
#define NBLK  256               /* 64-token tiles, 1 block/CU */

typedef __attribute__((ext_vector_type(8))) short bf16x8;
typedef __attribute__((ext_vector_type(16))) float f32x16;
typedef __attribute__((ext_vector_type(4))) unsigned int u32x4;

// pack two masked fp32 bit-patterns' high halves into one u32 of 2 bf16
#define PACK2(HI, LO) __builtin_amdgcn_perm((HI), (LO), 0x07060302u)

typedef union { unsigned u[4]; bf16x8 v; } b8u;

// ---------------------------------------------------------------------------
// pack_w: W fp32 [64][2048] -> exact 3-limb bf16 split, frag-ordered for
// 32x32x16 B-frags: ushort off = c*6144 + ks*3072 + tau*1024 + kgrp*512 + e*8
// (c = K-chunk of 32, ks = kstep half). Split is EXACT (masking; subtractions
// Sterbenz-exact); only ml/lm/ll cross terms dropped. Verified R10/R11.
// ---------------------------------------------------------------------------
__global__ void pack_w(const float* __restrict__ W,
                       unsigned short* __restrict__ Wp) {
  const int T = blockIdx.x * 256 + threadIdx.x;   // 16384 = 64c * 4j * 64e
  const int e = T & 63, j = (T >> 6) & 3, c = T >> 8;
  const float* src = W + (size_t)e * D_DIM + c * 32 + j * 8;
  float4 v0 = *(const float4*)src;
  float4 v1 = *(const float4*)(src + 4);
  float vv[8] = {v0.x, v0.y, v0.z, v0.w, v1.x, v1.y, v1.z, v1.w};
  unsigned hu[8], mu[8], lu[8];
#pragma unroll
  for (int q = 0; q < 8; ++q) {
    unsigned u = __float_as_uint(vv[q]);
    unsigned a = u & 0xffff0000u;
    float r = vv[q] - __uint_as_float(a);
    unsigned b = __float_as_uint(r) & 0xffff0000u;
    float r2 = r - __uint_as_float(b);
    unsigned d = __float_as_uint(r2) & 0xffff0000u;
    hu[q] = a; mu[q] = b; lu[q] = d;
  }
  u32x4 ph, pm, pl;
#pragma unroll
  for (int q = 0; q < 4; ++q) {     // ascending k pairs: lo k in low 16
    ph[q] = PACK2(hu[2 * q + 1], hu[2 * q]);
    pm[q] = PACK2(mu[2 * q + 1], mu[2 * q]);
    pl[q] = PACK2(lu[2 * q + 1], lu[2 * q]);
  }
  const size_t base = (size_t)c * 6144 + (j >> 1) * 3072 + (j & 1) * 512 + e * 8;
  *(u32x4*)(Wp + base)        = ph;   // tau 0
  *(u32x4*)(Wp + base + 1024) = pm;   // tau 1
  *(u32x4*)(Wp + base + 2048) = pl;   // tau 2
}

// ---------------------------------------------------------------------------
// Fused GEMM + gating. grid = 256 blocks x 512 thr (8 waves). Block =
// 64 tokens x 64 experts; wave kq owns K-eighth. MAIN LOOP: no LDS, no
// barriers; lane gathers its A rows (row=lane&31, kgroup=lane>>5 -- the
// 32x32x16 frag map; any k-permutation cancels since A and B share it),
// limb-splits in regs, feeds mfma_f32_32x32x16_bf16.
// R12: kstep-granular (K=16) dataflow. Per kstep: 4 x-float4 + 6 B-frags
// + 2 CVT + 4 MM6. Two named states, consume-then-refill, full unroll ->
// live set ~180 VGPR (R11's 240+ choked regalloc; loads serialized and
// HBM in-flight depth collapsed -- 45us vs 20.5us floor). With slack the
// compiler keeps >=1 kstep of loads (64 lines/wave, 512/CU) in flight.
// ---------------------------------------------------------------------------
struct KSst {
  float4 a0, a1, c0, c1;                 // x: rows 0-31 / 32-63, 8 floats ea
  bf16x8 B0h, B0m, B0l, B1h, B1m, B1l;   // W limbs: experts 0-31 / 32-63
};

__global__ __launch_bounds__(512)
void fused_router(const float* __restrict__ x,
                  const unsigned short* __restrict__ Wp,
                  float* __restrict__ out,
                  double* __restrict__ blk_ps,     // [256][64]
                  double* __restrict__ blk_z,      // [256]
                  unsigned* __restrict__ freq) {
  __shared__ float s_c[2][64][66];                 // 33.8 KB, staged combine
  __shared__ float s_m[64], s_inv[64];
  __shared__ unsigned hist[64];
  const int tid  = threadIdx.x;
  const int lane = tid & 63;
  const int kq   = tid >> 6;      // wave = K-eighth
  const int T0   = blockIdx.x * 64;
  if (tid < 64) hist[tid] = 0u;

  const int r  = lane & 31;       // token row within 32-tile / expert col
  const int kg = lane >> 5;       // k-group (0/1) within K=16 step
  const float* xa = x + (size_t)(T0 + r) * D_DIM + kq * KQ + kg * 8;
  const float* xc = xa + (size_t)32 * D_DIM;
  const unsigned short* bq = Wp + (size_t)(kq * 8) * 6144 + kg * 512 + r * 8;

  f32x16 acc00 = (f32x16)0.f, acc01 = (f32x16)0.f;   // rows 0-31 x e-halves
  f32x16 acc10 = (f32x16)0.f, acc11 = (f32x16)0.f;   // rows 32-63

#define CVT8(V0, V1, OH, OM, OL)                                            \
  do {                                                                      \
    float vv[8] = {(V0).x, (V0).y, (V0).z, (V0).w,                          \
                   (V1).x, (V1).y, (V1).z, (V1).w};                         \
    unsigned hu[8], mu[8], lu[8];                                           \
    _Pragma("unroll") for (int q = 0; q < 8; ++q) {                         \
      unsigned u = __float_as_uint(vv[q]);                                  \
      unsigned a = u & 0xffff0000u;                                         \
      float rr = vv[q] - __uint_as_float(a);                                \
      unsigned b = __float_as_uint(rr) & 0xffff0000u;                       \
      float r2 = rr - __uint_as_float(b);                                   \
      unsigned d = __float_as_uint(r2) & 0xffff0000u;                       \
      hu[q] = a; mu[q] = b; lu[q] = d;                                      \
    }                                                                       \
    b8u th, tm, tl;                                                         \
    _Pragma("unroll") for (int q = 0; q < 4; ++q) {                         \
      th.u[q] = PACK2(hu[2 * q + 1], hu[2 * q]);                            \
      tm.u[q] = PACK2(mu[2 * q + 1], mu[2 * q]);                            \
      tl.u[q] = PACK2(lu[2 * q + 1], lu[2 * q]);                            \
    }                                                                       \
    OH = th.v; OM = tm.v; OL = tl.v;                                        \
  } while (0)

#define MM6(AH, AM, AL, BH, BM, BL, ACC)                                      \
    ACC = __builtin_amdgcn_mfma_f32_32x32x16_bf16(AH, BH, ACC, 0, 0, 0);      \
    ACC = __builtin_amdgcn_mfma_f32_32x32x16_bf16(AH, BM, ACC, 0, 0, 0);      \
    ACC = __builtin_amdgcn_mfma_f32_32x32x16_bf16(AM, BH, ACC, 0, 0, 0);      \
    ACC = __builtin_amdgcn_mfma_f32_32x32x16_bf16(AH, BL, ACC, 0, 0, 0);      \
    ACC = __builtin_amdgcn_mfma_f32_32x32x16_bf16(AM, BM, ACC, 0, 0, 0);      \
    ACC = __builtin_amdgcn_mfma_f32_32x32x16_bf16(AL, BH, ACC, 0, 0, 0)

#define LOADS(S, KS)                                                        \
  do {                                                                      \
    const float* xp_ = xa + (KS) * 16;                                      \
    const float* xq_ = xc + (KS) * 16;                                      \
    S.a0 = *(const float4*)(xp_);  S.a1 = *(const float4*)(xp_ + 4);        \
    S.c0 = *(const float4*)(xq_);  S.c1 = *(const float4*)(xq_ + 4);        \
    const unsigned short* bk_ = bq + (size_t)(KS) * 3072;                   \
    S.B0h = *(const bf16x8*)(bk_);                                          \
    S.B0m = *(const bf16x8*)(bk_ + 1024);                                   \
    S.B0l = *(const bf16x8*)(bk_ + 2048);                                   \
    S.B1h = *(const bf16x8*)(bk_ + 256);                                    \
    S.B1m = *(const bf16x8*)(bk_ + 256 + 1024);                             \
    S.B1l = *(const bf16x8*)(bk_ + 256 + 2048);                             \
  } while (0)

#define CONSUME(S)                                                          \
  {                                                                         \
    bf16x8 Ah, Am, Al;                                                      \
    CVT8(S.a0, S.a1, Ah, Am, Al);                                           \
    MM6(Ah, Am, Al, S.B0h, S.B0m, S.B0l, acc00);                            \
    MM6(Ah, Am, Al, S.B1h, S.B1m, S.B1l, acc01);                            \
  }                                                                         \
  {                                                                         \
    bf16x8 Ch, Cm, Cl;                                                      \
    CVT8(S.c0, S.c1, Ch, Cm, Cl);                                           \
    MM6(Ch, Cm, Cl, S.B0h, S.B0m, S.B0l, acc10);                            \
    MM6(Ch, Cm, Cl, S.B1h, S.B1m, S.B1l, acc11);                            \
  }

  KSst S0, S1;
  LOADS(S0, 0);
  LOADS(S1, 1);
#pragma unroll
  for (int ks = 0; ks < NKS; ks += 2) {
    CONSUME(S0);
    if (ks + 2 < NKS) LOADS(S0, ks + 2);
    CONSUME(S1);
    if (ks + 3 < NKS) LOADS(S1, ks + 3);
  }
#undef CONSUME
#undef LOADS
#undef MM6
#undef CVT8

  // ---- staged 2-slot combine of 8 K-partials ----
  // C/D row-in-tile = (reg&3) + 8*(reg>>2) + 4*kg  [m74/m101-verified]
  const int slot = kq & 1;
#define SCAT(OP)                                                            \
  _Pragma("unroll") for (int reg = 0; reg < 16; ++reg) {                    \
    const int tl_ = (reg & 3) + 8 * (reg >> 2) + 4 * kg;                    \
    s_c[slot][tl_][r]           OP acc00[reg];                              \
    s_c[slot][tl_][32 + r]      OP acc01[reg];                              \
    s_c[slot][32 + tl_][r]      OP acc10[reg];                              \
    s_c[slot][32 + tl_][32 + r] OP acc11[reg];                              \
  }
  if (kq < 2) SCAT(=);
  __syncthreads();
  if (kq == 2 || kq == 3) SCAT(+=);
  __syncthreads();
  if (kq == 4 || kq == 5) SCAT(+=);
  __syncthreads();
  if (kq == 6 || kq == 7) SCAT(+=);
  __syncthreads();
#undef SCAT
  {   // fold slot1 into slot0: all 512 threads
    const int t = tid >> 3, e0 = (tid & 7) * 8;
#pragma unroll
    for (int q = 0; q < 8; ++q)
      s_c[0][t][e0 + q] += s_c[1][t][e0 + q];
  }
  __syncthreads();

  // ---- per-token: softmax stats, top-2, gates (R9-proven) ----
  if (tid < 64) {
    const int t = tid;
    float m = -3.402823466e38f;
#pragma unroll
    for (int e = 0; e < 64; ++e) m = fmaxf(m, s_c[0][t][e]);
    float sum = 0.f;
#pragma unroll
    for (int e = 0; e < 64; ++e) sum += __expf(s_c[0][t][e] - m);
    const float lse = m + __logf(sum);
    const float inv = 1.0f / sum;
    s_m[t] = m;
    s_inv[t] = inv;

    float v0 = s_c[0][t][0], v1 = -3.402823466e38f;
    int i0 = 0, i1 = 0;
#pragma unroll
    for (int e = 1; e < 64; ++e) {   // strict > keeps lowest idx (lax.top_k)
      float le = s_c[0][t][e];
      bool g0 = le > v0;
      bool g1 = le > v1;
      float nv1 = g0 ? v0 : (g1 ? le : v1);
      int   ni1 = g0 ? i0 : (g1 ? e  : i1);
      v0 = g0 ? le : v0;
      i0 = g0 ? e  : i0;
      v1 = nv1; i1 = ni1;
    }
    float dd = __expf(v1 - v0);
    float g0 = 1.0f / (1.0f + dd);
    float g1 = dd * g0;

    const int tg = T0 + t;
    out[tg * 2 + 0] = (float)i0;
    out[tg * 2 + 1] = (float)i1;
    out[2 * N_TOK + tg * 2 + 0] = g0;
    out[2 * N_TOK + tg * 2 + 1] = g1;

    atomicAdd(&hist[i0], 1u);
    atomicAdd(&hist[i1], 1u);

    float z = lse * lse;
    z += __shfl_xor(z, 32, 64);
    z += __shfl_xor(z, 16, 64);
    z += __shfl_xor(z, 8, 64);
    z += __shfl_xor(z, 4, 64);
    z += __shfl_xor(z, 2, 64);
    z += __shfl_xor(z, 1, 64);
    if (tid == 0) blk_z[blockIdx.x] = (double)z;
  }
  __syncthreads();

  // ---- per-expert prob column sums (wave 1) + freq flush ----
  if (tid >= 64 && tid < 128) {
    const int e = tid - 64;
    float cs2 = 0.f;
#pragma unroll 8
    for (int t = 0; t < 64; ++t)
      cs2 += __expf(s_c[0][t][e] - s_m[t]) * s_inv[t];
    blk_ps[(size_t)blockIdx.x * 64 + e] = (double)cs2;
  }
  if (tid < 64 && hist[tid]) atomicAdd(&freq[tid], hist[tid]);
}

// ---------------------------------------------------------------------------
// Finalize: sum per-block partials, switchloss + 0.1*z_loss (1 block, 64 thr)
// ---------------------------------------------------------------------------
__global__ void finalize(const double* __restrict__ blk_ps,
                         const double* __restrict__ blk_z,
                         const unsigned* __restrict__ freq,
                         float* __restrict__ out_loss) {
  const int lane = threadIdx.x;
  double p = 0.0;
  for (int b = 0; b < NBLK; ++b) p += blk_ps[(size_t)b * 64 + lane];
  double zt = 0.0;
#pragma unroll
  for (int b = 0; b < NBLK / 64; ++b) zt += blk_z[lane * (NBLK / 64) + b];
#pragma unroll
  for (int off = 32; off >= 1; off >>= 1) zt += __shfl_xor(zt, off, 64);

  double f = (double)freq[lane];
  double pa = fabs(p);
  double fa = fabs(f);
#pragma unroll
  for (int off = 32; off >= 1; off >>= 1) {
    pa += __shfl_xor(pa, off, 64);
    fa += __shfl_xor(fa, off, 64);
  }
  pa = pa > 1e-12 ? pa : 1e-12;
  fa = fa > 1e-12 ? fa : 1e-12;

  double s = (p / pa) * (f / fa);
#pragma unroll
  for (int off = 32; off >= 1; off >>= 1) s += __shfl_xor(s, off, 64);

  if (lane == 0) {
    double switchloss = 64.0 * s;
    double z_loss = zt / (double)N_TOK;
    out_loss[0] = (float)(switchloss + 0.1 * z_loss);
  }
}

extern "C" void kernel_launch(void* const* d_in, const int* in_sizes, int n_in,
                              void* d_out, int out_size, void* d_ws, size_t ws_size,
                              hipStream_t stream) {
  const float* x = (const float*)d_in[0];
  const float* W = (const float*)d_in[1];
  float* out = (float*)d_out;

  double* blk_ps = (double*)d_ws;                        // 256*64*8 = 128 KB
  double* blk_z  = blk_ps + NBLK * 64;                   // 2 KB
  unsigned* freq = (unsigned*)(blk_z + NBLK);            // 256 B
  size_t woff = (NBLK * 64 * 8 + NBLK * 8 + 64 * 4 + 255) & ~(size_t)255;
  unsigned short* Wp = (unsigned short*)((char*)d_ws + woff);  // 768 KB

  hipMemsetAsync(freq, 0, 64 * sizeof(unsigned), stream);

  pack_w<<<64, 256, 0, stream>>>(W, Wp);
  fused_router<<<NBLK, 512, 0, stream>>>(x, Wp, out, blk_ps, blk_z, freq);
  finalize<<<1, 64, 0, stream>>>(blk_ps, blk_z, freq, out + 4 * N_TOK);
}